// Round 1
// baseline (557.127 us; speedup 1.0000x reference)
//
#include <hip/hip_runtime.h>

#define B_ 1024
#define D_ 784
#define H_ 1024
#define LOG2E 1.4426950408889634f

// ---------- prep: out[b*D + i] = bias[i] ----------
__global__ __launch_bounds__(256) void init_out_kernel(const float* __restrict__ bias,
                                                       float* __restrict__ out) {
    int i = blockIdx.x * 256 + threadIdx.x;
    if (i < D_) out[(size_t)blockIdx.y * D_ + i] = bias[i];
}

// ---------- prep: Wt[i*H + h] = W[h*D + i] * log2e ----------
__global__ __launch_bounds__(256) void transpose_scale_W(const float* __restrict__ W,
                                                         float* __restrict__ Wt) {
    __shared__ float t[32][33];
    int i0 = blockIdx.x * 32;               // D dim
    int h0 = blockIdx.y * 32;               // H dim
    int tx = threadIdx.x & 31, ty = threadIdx.x >> 5;   // 32 x 8
#pragma unroll
    for (int j = 0; j < 4; ++j) {
        int h = h0 + ty + j * 8;
        int i = i0 + tx;
        float v = 0.f;
        if (i < D_) v = W[(size_t)h * D_ + i] * LOG2E;
        t[ty + j * 8][tx] = v;              // t[h_local][i_local]
    }
    __syncthreads();
#pragma unroll
    for (int j = 0; j < 4; ++j) {
        int i = i0 + ty + j * 8;
        int h = h0 + tx;
        if (i < D_) Wt[(size_t)i * H_ + h] = t[tx][ty + j * 8];
    }
}

// ---------- DPP helpers: reduce both 32-lane halves simultaneously ----------
template <int CTRL>
__device__ __forceinline__ float dpp_add(float p) {
    int s = __builtin_amdgcn_update_dpp(0, __float_as_int(p), CTRL, 0xf, 0xf, true);
    return p + __int_as_float(s);
}

__device__ __forceinline__ float reduce_halves(float p) {
    p = dpp_add<0x111>(p);   // row_shr:1
    p = dpp_add<0x112>(p);   // row_shr:2
    p = dpp_add<0x114>(p);   // row_shr:4
    p = dpp_add<0x118>(p);   // row_shr:8  -> lane15/31/47/63 hold 16-sums
    p = dpp_add<0x142>(p);   // row_bcast15 -> lane31 = sum(0..31), lane63 = sum(32..63)
    return p;
}

// ---------- main NADE scan ----------
__global__ __launch_bounds__(256, 4) void nade_main(
    const float* __restrict__ px,   // [B, D]
    const float* __restrict__ c,    // [H]
    const float* __restrict__ V,    // [D, H]
    const float* __restrict__ Wt,   // [D, H], pre-scaled by log2e
    float* __restrict__ out)        // [B, D], pre-init to bias
{
    const int lane = threadIdx.x & 63;
    const int wid  = threadIdx.x >> 6;
    const int gw   = blockIdx.x * 4 + wid;   // 0..4095
    const int hb   = gw & 7;                 // h-chunk [0,8)
    const int rp   = gw >> 3;                // row pair [0,512)
    const int half = lane >> 5;
    const int row  = rp * 2 + half;
    const int h0   = hb * 128 + (lane & 31) * 4;

    // accumulator in log2 domain: A = a * log2e
    float A[4];
#pragma unroll
    for (int k = 0; k < 4; ++k) A[k] = c[h0 + k] * LOG2E;

    const float* vp = V  + h0;
    const float* wp = Wt + h0;
    const float* xp = px + (size_t)row * D_;
    float*       op = out + (size_t)row * D_;

    float4 vv = *(const float4*)vp;
    float4 ww = *(const float4*)wp;
    float  x  = xp[0];

    for (int i = 0; i < D_ - 1; ++i) {
        // prefetch next step
        float4 vn = *(const float4*)(vp + (size_t)(i + 1) * H_);
        float4 wn = *(const float4*)(wp + (size_t)(i + 1) * H_);
        float  xn = xp[i + 1];

        float va[4] = {vv.x, vv.y, vv.z, vv.w};
        float wa[4] = {ww.x, ww.y, ww.z, ww.w};
        float p = 0.f;
#pragma unroll
        for (int k = 0; k < 4; ++k) {
            float e = __builtin_amdgcn_exp2f(-A[k]);   // exp2(-A)
            float h = __builtin_amdgcn_rcpf(1.0f + e); // sigmoid
            p = fmaf(va[k], h, p);
            A[k] = fmaf(wa[k], x, A[k]);
        }
        p = reduce_halves(p);
        if ((lane & 31) == 31) unsafeAtomicAdd(op + i, p);

        vv = vn; ww = wn; x = xn;
    }
    // last step (i = D_-1), no prefetch
    {
        const int i = D_ - 1;
        float va[4] = {vv.x, vv.y, vv.z, vv.w};
        float wa[4] = {ww.x, ww.y, ww.z, ww.w};
        float p = 0.f;
#pragma unroll
        for (int k = 0; k < 4; ++k) {
            float e = __builtin_amdgcn_exp2f(-A[k]);
            float h = __builtin_amdgcn_rcpf(1.0f + e);
            p = fmaf(va[k], h, p);
            A[k] = fmaf(wa[k], x, A[k]);
        }
        p = reduce_halves(p);
        if ((lane & 31) == 31) unsafeAtomicAdd(op + i, p);
    }
}

extern "C" void kernel_launch(void* const* d_in, const int* in_sizes, int n_in,
                              void* d_out, int out_size, void* d_ws, size_t ws_size,
                              hipStream_t stream) {
    const float* px   = (const float*)d_in[0];  // [B, D]
    const float* W    = (const float*)d_in[1];  // [H, D]
    const float* c    = (const float*)d_in[2];  // [H]
    const float* V    = (const float*)d_in[3];  // [D, H]
    const float* bias = (const float*)d_in[4];  // [D]
    float* out = (float*)d_out;                 // [B, D]
    float* Wt  = (float*)d_ws;                  // [D, H] scratch (3.2 MB)

    // prep
    transpose_scale_W<<<dim3((D_ + 31) / 32, H_ / 32), 256, 0, stream>>>(W, Wt);
    init_out_kernel<<<dim3((D_ + 255) / 256, B_), 256, 0, stream>>>(bias, out);

    // main scan: 1024 blocks x 256 threads = 4096 independent waves
    nade_main<<<dim3(B_), 256, 0, stream>>>(px, c, V, Wt, out);
}